// Round 8
// baseline (226.119 us; speedup 1.0000x reference)
//
#include <hip/hip_runtime.h>

// BasicBlock: y = relu(bn2(conv2(relu(bn1(conv1(x, we1))), we2)) + x)
// we{1,2} = sum_e alpha[e]*w{1,2}[e].
//
// bf16 implicit-GEMM conv, mfma_f32_16x16x32_bf16, staged from padded,
// chunk-swizzled NHWC bf16 images (slot = c8 ^ ((2h+w)&7) within 128B px).
//
// R8: R6's proven core + R7's deep pipeline, WITHOUT the volatile-weight
// spill disaster (R7: VGPR stayed 128 -> 144 forced-live regs spilled to
// scratch, +126MB traffic). TILES=4 for both passes: stage(t+2) issued in
// each epilogue so EVERY compute phase has a 23KB stage in flight (R6's
// TILES=2 ran dry on odd tiles -> 2.85 TB/s ~ 50% duty cycle). PASS1 also
// prefetches the fp32 residual before compute. All waits are counted
// vmcnt(N), loads-only sound: load L is complete after vmcnt(N) whenever
// N <= #loads younger than L (stores in the window only add conservatism).

typedef __bf16 bf16x8 __attribute__((ext_vector_type(8)));
typedef float f32x4 __attribute__((ext_vector_type(4)));
typedef unsigned short u16;
typedef u16 u16x8 __attribute__((ext_vector_type(8)));

#define NH 112
#define NW 112
#define PH 114
#define PW 114
#define PROWB (PW * 128)  // 14592 bytes per padded NHWC row
#define BUFB 23040        // one A-tile buffer: 10 rows * 18 px * 128 B

#define WAITVM(n) asm volatile("s_waitcnt vmcnt(" #n ")" ::: "memory")
#define SCHEDB __builtin_amdgcn_sched_barrier(0)

__device__ __forceinline__ u16 f2b(float f) {
  unsigned u = __builtin_bit_cast(unsigned, f);
  u += 0x7FFFu + ((u >> 16) & 1u);
  return (u16)(u >> 16);
}

__device__ __forceinline__ void gl_lds16(const void* g, void* l) {
  __builtin_amdgcn_global_load_lds(
      (const __attribute__((address_space(1))) unsigned int*)g,
      (__attribute__((address_space(3))) unsigned int*)l, 16, 0, 0);
}

// ---------------------------------------------------------------------------
__global__ void border_zero(u16* __restrict__ a, u16* __restrict__ bbuf) {
  int idx = blockIdx.x * 256 + threadIdx.x;  // 2*32*452*8 = 231424 chunks
  if (idx >= 231424) return;
  int c8 = idx & 7;
  int t = idx >> 3;
  int buf = t >= 14464;
  t -= buf * 14464;
  int img = t / 452, e = t % 452;
  int h, w;
  if (e < 114) { h = 0; w = e; }
  else if (e < 228) { h = 113; w = e - 114; }
  else if (e < 340) { h = e - 227; w = 0; }
  else { h = e - 339; w = 113; }
  u16* base = buf ? bbuf : a;
  u16x8 z = {0, 0, 0, 0, 0, 0, 0, 0};
  *reinterpret_cast<u16x8*>(base + (((long)img * PH + h) * PW + w) * 64 + c8 * 8) = z;
}

// ---------------------------------------------------------------------------
// x NCHW fp32 -> x_pad NHWC bf16 (padded + chunk-swizzled). block = (b,h).
__global__ __launch_bounds__(256) void transform_kernel(const float* __restrict__ x,
                                                        u16* __restrict__ xpad) {
  __shared__ alignas(16) u16 t[7168];  // [112 px][64 ch], xor-swizzled bytes
  int tid = threadIdx.x, bid = blockIdx.x;
  int b = bid / NH, h = bid % NH;
  const float* src = x + (long)b * 64 * 12544 + h * NW;
  f32x4 v[7];
#pragma unroll
  for (int it = 0; it < 7; ++it) {
    int fid = it * 256 + tid;  // 1792 = 64 ch * 28 quads
    int c = fid / 28, wq = fid % 28;
    v[it] = *reinterpret_cast<const f32x4*>(src + c * 12544 + wq * 4);
  }
#pragma unroll
  for (int it = 0; it < 7; ++it) {
    int fid = it * 256 + tid;
    int c = fid / 28, wq = fid % 28;
    int key = (wq & 7) << 4;
#pragma unroll
    for (int j = 0; j < 4; ++j) {
      int px = wq * 4 + j;
      *reinterpret_cast<u16*>((char*)t + px * 128 + ((c * 2) ^ key)) = f2b(v[it][j]);
    }
  }
  __syncthreads();
  int hp = h + 1;
  u16* rowb = xpad + (((long)b * PH + hp) * PW) * 64;
#pragma unroll
  for (int it = 0; it < 4; ++it) {
    int cidx = it * 256 + tid;
    if (cidx < 896) {  // 112 px * 8 chunks
      int c8 = cidx & 7, px = cidx >> 3;
      int lchunk = c8 ^ ((px >> 2) & 7);
      u16x8 vv = *reinterpret_cast<const u16x8*>((const char*)t + px * 128 + lchunk * 16);
      int wp = px + 1;
      int gkey = (2 * hp + wp) & 7;
      *reinterpret_cast<u16x8*>(rowb + (long)wp * 64 + ((c8 ^ gkey) * 8)) = vv;
    }
  }
}

// ---------------------------------------------------------------------------
// fold experts -> w_eff bf16 [kpos][o][i] + folded BN constants
__global__ void prep_kernel(
    const float* __restrict__ w1, const float* __restrict__ w2,
    const float* __restrict__ alpha,
    const float* __restrict__ g1, const float* __restrict__ b1,
    const float* __restrict__ m1, const float* __restrict__ v1,
    const float* __restrict__ g2, const float* __restrict__ b2,
    const float* __restrict__ m2, const float* __restrict__ v2,
    u16* __restrict__ weff1, u16* __restrict__ weff2, float* __restrict__ bnc) {
  int idx = blockIdx.x * 256 + threadIdx.x;  // 36864
  if (idx < 36864) {
    int i = idx & 63;
    int o = (idx >> 6) & 63;
    int kpos = idx >> 12;
    int base = (o * 64 + i) * 9 + kpos;  // src [E][O][I][3][3]
    float a1 = 0.f, a2 = 0.f;
#pragma unroll
    for (int e = 0; e < 10; ++e) {
      float al = alpha[e];
      a1 += al * w1[e * 36864 + base];
      a2 += al * w2[e * 36864 + base];
    }
    weff1[idx] = f2b(a1);
    weff2[idx] = f2b(a2);
  }
  if (blockIdx.x == 0 && threadIdx.x < 64) {
    int c = threadIdx.x;
    float i1 = g1[c] * rsqrtf(v1[c] + 1e-5f);
    float i2 = g2[c] * rsqrtf(v2[c] + 1e-5f);
    bnc[c] = i1;
    bnc[64 + c] = b1[c] - m1[c] * i1;
    bnc[128 + c] = i2;
    bnc[192 + c] = b2[c] - m2[c] * i2;
  }
}

// ---------------------------------------------------------------------------
// conv pass. 8x16 px x 64 oc per tile, TILES tiles/block over 2 LDS buffers,
// 256 threads (4 waves: wave = 4 Mfrags(rows) x 2 Nfrags).
// PASS 0 (TILES=4, grid 784): x_pad -> bn1+relu -> y1_pad (swizzled NHWC)
// PASS 1 (TILES=4, grid 784): y1_pad -> bn2 + residual(x) + relu -> out
// ---------------------------------------------------------------------------
template <int PASS, int TILES>
__global__ __launch_bounds__(256, 2) void conv_bn_kernel(
    const u16* __restrict__ xin, const float* __restrict__ x,
    const u16* __restrict__ weff, const float* __restrict__ bnc,
    u16* __restrict__ ypad, float* __restrict__ out) {
  __shared__ alignas(1024) char smem[2 * BUFB];

  const int tid = threadIdx.x, lane = tid & 63, wv = tid >> 6;
  const int ol = lane & 15, kg = (lane >> 4) & 3;
  const int f0 = (wv >> 1) * 4, nf0 = (wv & 1) * 2;

  float inv[2], bias[2];
#pragma unroll
  for (int j = 0; j < 2; ++j) {
    int o = (nf0 + j) * 16 + ol;
    inv[j] = bnc[PASS * 128 + o];
    bias[j] = bnc[PASS * 128 + 64 + o];
  }

  bf16x8 wf[3][3][2][2];  // [kh][kw][ks][j] — compiler-managed residency
#pragma unroll
  for (int kh = 0; kh < 3; ++kh)
#pragma unroll
    for (int kw = 0; kw < 3; ++kw)
#pragma unroll
      for (int ks = 0; ks < 2; ++ks)
#pragma unroll
        for (int j = 0; j < 2; ++j)
          wf[kh][kw][ks][j] = __builtin_bit_cast(
              bf16x8, *reinterpret_cast<const u16x8*>(
                          weff + (((kh * 3 + kw) * 64 + (nf0 + j) * 16 + ol) * 64 +
                                  ks * 32 + kg * 8)));
  WAITVM(0);
  SCHEDB;

  // tile decode (XCD-chunked: each XCD gets a contiguous range -> L2 locality)
  constexpr int CPX = 98;  // 784 blocks = 8 * 98
  int sb = (blockIdx.x & 7) * CPX + (blockIdx.x >> 3);
  int tb[TILES], th0[TILES], tw0[TILES];
#pragma unroll
  for (int t = 0; t < TILES; ++t) {
    int tt = sb * TILES + t;
    tb[t] = tt / 98;
    int r = tt % 98;
    th0[t] = (r / 7) * 8;
    tw0[t] = (r % 7) * 16;
  }

  // stage one 10x18 window (1440 chunks; waves issue 6,6,6,5 insts)
  auto stage = [&](int t, int boff) {
#pragma unroll
    for (int k = 0; k < 6; ++k) {
      int i = wv + k * 4;
      if (i < 23) {
        int cb = i * 64 + lane;
        if (cb < 1440) {
          int row = cb / 144, rem = cb - row * 144;
          gl_lds16((const char*)(xin + (((long)tb[t] * PH + th0[t]) * PW + tw0[t]) * 64) +
                       (long)row * PROWB + rem * 16,
                   smem + boff + cb * 16);
        }
      }
    }
  };

  f32x4 acc[4][2];
  auto compute = [&](int boff) {
#pragma unroll
    for (int mf = 0; mf < 4; ++mf)
#pragma unroll
      for (int j = 0; j < 2; ++j) acc[mf][j] = f32x4{0.f, 0.f, 0.f, 0.f};
#pragma unroll
    for (int kw = 0; kw < 3; ++kw)
#pragma unroll
      for (int ks = 0; ks < 2; ++ks) {
        bf16x8 a[6];
#pragma unroll
        for (int u = 0; u < 6; ++u) {
          int rr = f0 + u, col = ol + kw;
          int slot = ((ks << 2) | kg) ^ ((2 * rr + col) & 7);
          a[u] = *reinterpret_cast<const bf16x8*>(smem + boff + (rr * 18 + col) * 128 +
                                                  slot * 16);
        }
#pragma unroll
        for (int kh = 0; kh < 3; ++kh)
#pragma unroll
          for (int mf = 0; mf < 4; ++mf)
#pragma unroll
            for (int j = 0; j < 2; ++j)
              acc[mf][j] = __builtin_amdgcn_mfma_f32_16x16x32_bf16(
                  a[mf + kh], wf[kh][kw][ks][j], acc[mf][j], 0, 0, 0);
      }
  };

  f32x4 xr[2][2][2];  // PASS1 residual prefetch [half][m][j]
  auto xload = [&](int t) {
#pragma unroll
    for (int half = 0; half < 2; ++half)
#pragma unroll
      for (int m = 0; m < 2; ++m)
#pragma unroll
        for (int j = 0; j < 2; ++j) {
          int h = th0[t] + f0 + half * 2 + m;
          xr[half][m][j] = *reinterpret_cast<const f32x4*>(
              x + (((tb[t] * 64 + (nf0 + j) * 16 + ol) * NH + h) * NW + tw0[t] + kg * 4));
        }
  };
  auto xstore = [&](int t) {
#pragma unroll
    for (int half = 0; half < 2; ++half)
#pragma unroll
      for (int m = 0; m < 2; ++m)
#pragma unroll
        for (int j = 0; j < 2; ++j) {
          int mf = half * 2 + m;
          int h = th0[t] + f0 + mf;
          f32x4 vv;
#pragma unroll
          for (int rg = 0; rg < 4; ++rg)
            vv[rg] = fmaxf(acc[mf][j][rg] * inv[j] + bias[j] + xr[half][m][j][rg], 0.f);
          *reinterpret_cast<f32x4*>(
              out + (((tb[t] * 64 + (nf0 + j) * 16 + ol) * NH + h) * NW + tw0[t] + kg * 4)) =
              vv;
        }
  };

  auto ysw = [&](int boff) {  // PASS0: bn1+relu -> bf16 transpose staging
    u16* ys = reinterpret_cast<u16*>(smem + boff);  // [128 px][72]
#pragma unroll
    for (int mf = 0; mf < 4; ++mf)
#pragma unroll
      for (int j = 0; j < 2; ++j) {
        int o = (nf0 + j) * 16 + ol;
#pragma unroll
        for (int rg = 0; rg < 4; ++rg) {
          int p = (f0 + mf) * 16 + kg * 4 + rg;
          ys[p * 72 + o] = f2b(fmaxf(acc[mf][j][rg] * inv[j] + bias[j], 0.f));
        }
      }
  };
  auto ysr = [&](int t, int boff) {  // coalesced swizzled NHWC store
    u16* ys = reinterpret_cast<u16*>(smem + boff);
#pragma unroll
    for (int it = 0; it < 4; ++it) {
      int cidx = it * 256 + tid;  // 1024 chunks
      int c8 = cidx & 7, p = cidx >> 3;
      int hp = th0[t] + (p >> 4) + 1, wp = tw0[t] + (p & 15) + 1;
      int gkey = (2 * hp + wp) & 7;
      *reinterpret_cast<u16x8*>(ypad + (((long)tb[t] * PH + hp) * PW + wp) * 64 +
                                ((c8 ^ gkey) * 8)) =
          *reinterpret_cast<const u16x8*>(ys + p * 72 + c8 * 8);
    }
  };

  if constexpr (PASS == 1) {
    stage(0, 0);
    xload(0);
    stage(1, BUFB);
    if (wv < 3) WAITVM(14); else WAITVM(13);  // S0 done (younger = X0+S1)
    SCHEDB;
    __builtin_amdgcn_s_barrier();
    SCHEDB;
#pragma unroll
    for (int t = 0; t < TILES; ++t) {
      const int boff = (t & 1) * BUFB;
      compute(boff);
      if (t < TILES - 1) { if (wv < 3) WAITVM(6); else WAITVM(5); }  // X_t done
      else WAITVM(0);
      SCHEDB;
      __builtin_amdgcn_s_barrier();  // all waves done reading buf_t
      SCHEDB;
      xstore(t);
      if (t + 1 < TILES) xload(t + 1);
      if (t + 2 < TILES) stage(t + 2, boff);
      if (t < TILES - 2) { if (wv < 3) WAITVM(14); else WAITVM(13); }  // S_{t+1}
      else if (t == TILES - 2) WAITVM(8);
      SCHEDB;
      if (t < TILES - 1) { __builtin_amdgcn_s_barrier(); SCHEDB; }
    }
  } else {
    stage(0, 0);
    stage(1, BUFB);
    if (wv < 3) WAITVM(6); else WAITVM(5);  // S0 done (younger = S1)
    SCHEDB;
    __builtin_amdgcn_s_barrier();
    SCHEDB;
#pragma unroll
    for (int t = 0; t < TILES; ++t) {
      const int boff = (t & 1) * BUFB;
      compute(boff);
      SCHEDB;
      __builtin_amdgcn_s_barrier();  // buf_t free -> reuse as ys scratch
      SCHEDB;
      ysw(boff);
      asm volatile("s_waitcnt lgkmcnt(0)" ::: "memory");
      SCHEDB;
      __builtin_amdgcn_s_barrier();
      SCHEDB;
      WAITVM(0);  // S_{t+1} done (was in flight during compute -> cheap)
      SCHEDB;
      ysr(t, boff);
      if (t < TILES - 1) { __builtin_amdgcn_s_barrier(); SCHEDB; }
      if (t + 2 < TILES) stage(t + 2, boff);  // after barrier: ys reads done
    }
  }
}

// ---------------------------------------------------------------------------
extern "C" void kernel_launch(void* const* d_in, const int* in_sizes, int n_in,
                              void* d_out, int out_size, void* d_ws, size_t ws_size,
                              hipStream_t stream) {
  const float* x = (const float*)d_in[0];
  const float* w1 = (const float*)d_in[1];
  const float* w2 = (const float*)d_in[2];
  const float* alpha = (const float*)d_in[3];
  const float* g1 = (const float*)d_in[4];
  const float* b1 = (const float*)d_in[5];
  const float* m1 = (const float*)d_in[6];
  const float* v1 = (const float*)d_in[7];
  const float* g2 = (const float*)d_in[8];
  const float* b2 = (const float*)d_in[9];
  const float* m2 = (const float*)d_in[10];
  const float* v2 = (const float*)d_in[11];
  float* out = (float*)d_out;

  char* ws = (char*)d_ws;
  u16* weff1 = (u16*)ws;                 // 73728 B
  u16* weff2 = (u16*)(ws + 73728);       // 73728 B
  float* bnc = (float*)(ws + 147456);    // 1024 B
  u16* y1pad = (u16*)(ws + 148480);      // 32*114*114*64*2 = 53231616 B
  u16* xpad = (u16*)d_out;               // 53 MB <= 103 MB; dead before P1 writes

  border_zero<<<904, 256, 0, stream>>>(xpad, y1pad);
  transform_kernel<<<32 * NH, 256, 0, stream>>>(x, xpad);
  prep_kernel<<<144, 256, 0, stream>>>(w1, w2, alpha, g1, b1, m1, v1,
                                       g2, b2, m2, v2, weff1, weff2, bnc);
  conv_bn_kernel<0, 4><<<784, 256, 0, stream>>>(xpad, x, weff1, bnc, y1pad, nullptr);
  conv_bn_kernel<1, 4><<<784, 256, 0, stream>>>(y1pad, x, weff2, bnc, nullptr, out);
}

// Round 9
// 198.856 us; speedup vs baseline: 1.1371x; 1.1371x over previous
//
#include <hip/hip_runtime.h>

// BasicBlock: y = relu(bn2(conv2(relu(bn1(conv1(x, we1))), we2)) + x)
// we{1,2} = sum_e alpha[e]*w{1,2}[e].
//
// bf16 implicit-GEMM conv, mfma_f32_16x16x32_bf16, staged from padded,
// chunk-swizzled NHWC bf16 images (slot = c8 ^ ((2h+w)&7) within 128B px).
//
// R9: R6's register profile (no spills: VGPR=128, FETCH ~108MB) + a 4-tile
// pipeline. stage(t+2) is issued INSIDE epilogue(t) so computes 0..2 run
// with a 23KB stage in flight (R6's TILES=2 = 50% duty). R8's spills came
// from xr held across compute + big unroll: here xr lives only inside the
// epilogue, and is loaded BEFORE stage(t+2) so compiler xr-waits count 6
// younger stage-loads (vmcnt(6), pipeline survives). Gate soundness: after
// vmcnt(N), load L is retired whenever N <= #loads younger than L (loads
// retire oldest-first; stores can only inflate the count = conservative).

typedef __bf16 bf16x8 __attribute__((ext_vector_type(8)));
typedef float f32x4 __attribute__((ext_vector_type(4)));
typedef unsigned short u16;
typedef u16 u16x8 __attribute__((ext_vector_type(8)));

#define NH 112
#define NW 112
#define PH 114
#define PW 114
#define PROWB (PW * 128)  // 14592 bytes per padded NHWC row
#define BUFB 23040        // one A-tile buffer: 10 rows * 18 px * 128 B

#define WAITVM(n) asm volatile("s_waitcnt vmcnt(" #n ")" ::: "memory")
#define SCHEDB __builtin_amdgcn_sched_barrier(0)

__device__ __forceinline__ u16 f2b(float f) {
  unsigned u = __builtin_bit_cast(unsigned, f);
  u += 0x7FFFu + ((u >> 16) & 1u);
  return (u16)(u >> 16);
}

__device__ __forceinline__ void gl_lds16(const void* g, void* l) {
  __builtin_amdgcn_global_load_lds(
      (const __attribute__((address_space(1))) unsigned int*)g,
      (__attribute__((address_space(3))) unsigned int*)l, 16, 0, 0);
}

// ---------------------------------------------------------------------------
__global__ void border_zero(u16* __restrict__ a, u16* __restrict__ bbuf) {
  int idx = blockIdx.x * 256 + threadIdx.x;  // 2*32*452*8 = 231424 chunks
  if (idx >= 231424) return;
  int c8 = idx & 7;
  int t = idx >> 3;
  int buf = t >= 14464;
  t -= buf * 14464;
  int img = t / 452, e = t % 452;
  int h, w;
  if (e < 114) { h = 0; w = e; }
  else if (e < 228) { h = 113; w = e - 114; }
  else if (e < 340) { h = e - 227; w = 0; }
  else { h = e - 339; w = 113; }
  u16* base = buf ? bbuf : a;
  u16x8 z = {0, 0, 0, 0, 0, 0, 0, 0};
  *reinterpret_cast<u16x8*>(base + (((long)img * PH + h) * PW + w) * 64 + c8 * 8) = z;
}

// ---------------------------------------------------------------------------
// x NCHW fp32 -> x_pad NHWC bf16 (padded + chunk-swizzled). block = (b,h).
__global__ __launch_bounds__(256) void transform_kernel(const float* __restrict__ x,
                                                        u16* __restrict__ xpad) {
  __shared__ alignas(16) u16 t[7168];  // [112 px][64 ch], xor-swizzled bytes
  int tid = threadIdx.x, bid = blockIdx.x;
  int b = bid / NH, h = bid % NH;
  const float* src = x + (long)b * 64 * 12544 + h * NW;
  f32x4 v[7];
#pragma unroll
  for (int it = 0; it < 7; ++it) {
    int fid = it * 256 + tid;  // 1792 = 64 ch * 28 quads
    int c = fid / 28, wq = fid % 28;
    v[it] = *reinterpret_cast<const f32x4*>(src + c * 12544 + wq * 4);
  }
#pragma unroll
  for (int it = 0; it < 7; ++it) {
    int fid = it * 256 + tid;
    int c = fid / 28, wq = fid % 28;
    int key = (wq & 7) << 4;
#pragma unroll
    for (int j = 0; j < 4; ++j) {
      int px = wq * 4 + j;
      *reinterpret_cast<u16*>((char*)t + px * 128 + ((c * 2) ^ key)) = f2b(v[it][j]);
    }
  }
  __syncthreads();
  int hp = h + 1;
  u16* rowb = xpad + (((long)b * PH + hp) * PW) * 64;
#pragma unroll
  for (int it = 0; it < 4; ++it) {
    int cidx = it * 256 + tid;
    if (cidx < 896) {  // 112 px * 8 chunks
      int c8 = cidx & 7, px = cidx >> 3;
      int lchunk = c8 ^ ((px >> 2) & 7);
      u16x8 vv = *reinterpret_cast<const u16x8*>((const char*)t + px * 128 + lchunk * 16);
      int wp = px + 1;
      int gkey = (2 * hp + wp) & 7;
      *reinterpret_cast<u16x8*>(rowb + (long)wp * 64 + ((c8 ^ gkey) * 8)) = vv;
    }
  }
}

// ---------------------------------------------------------------------------
// fold experts -> w_eff bf16 [kpos][o][i] + folded BN constants
__global__ void prep_kernel(
    const float* __restrict__ w1, const float* __restrict__ w2,
    const float* __restrict__ alpha,
    const float* __restrict__ g1, const float* __restrict__ b1,
    const float* __restrict__ m1, const float* __restrict__ v1,
    const float* __restrict__ g2, const float* __restrict__ b2,
    const float* __restrict__ m2, const float* __restrict__ v2,
    u16* __restrict__ weff1, u16* __restrict__ weff2, float* __restrict__ bnc) {
  int idx = blockIdx.x * 256 + threadIdx.x;  // 36864
  if (idx < 36864) {
    int i = idx & 63;
    int o = (idx >> 6) & 63;
    int kpos = idx >> 12;
    int base = (o * 64 + i) * 9 + kpos;  // src [E][O][I][3][3]
    float a1 = 0.f, a2 = 0.f;
#pragma unroll
    for (int e = 0; e < 10; ++e) {
      float al = alpha[e];
      a1 += al * w1[e * 36864 + base];
      a2 += al * w2[e * 36864 + base];
    }
    weff1[idx] = f2b(a1);
    weff2[idx] = f2b(a2);
  }
  if (blockIdx.x == 0 && threadIdx.x < 64) {
    int c = threadIdx.x;
    float i1 = g1[c] * rsqrtf(v1[c] + 1e-5f);
    float i2 = g2[c] * rsqrtf(v2[c] + 1e-5f);
    bnc[c] = i1;
    bnc[64 + c] = b1[c] - m1[c] * i1;
    bnc[128 + c] = i2;
    bnc[192 + c] = b2[c] - m2[c] * i2;
  }
}

// ---------------------------------------------------------------------------
// conv pass. 8x16 px x 64 oc per tile, TILES=4 tiles/block over 2 LDS bufs,
// 256 threads (4 waves: wave = 4 Mfrags(rows) x 2 Nfrags), grid 784.
// PASS 0: x_pad -> bn1+relu -> y1_pad (swizzled NHWC bf16)
// PASS 1: y1_pad -> bn2 + residual(x) + relu -> out (NCHW f32)
// ---------------------------------------------------------------------------
template <int PASS, int TILES>
__global__ __launch_bounds__(256, 2) void conv_bn_kernel(
    const u16* __restrict__ xin, const float* __restrict__ x,
    const u16* __restrict__ weff, const float* __restrict__ bnc,
    u16* __restrict__ ypad, float* __restrict__ out) {
  __shared__ alignas(1024) char smem[2 * BUFB];

  const int tid = threadIdx.x, lane = tid & 63, wv = tid >> 6;
  const int ol = lane & 15, kg = (lane >> 4) & 3;
  const int f0 = (wv >> 1) * 4, nf0 = (wv & 1) * 2;

  float inv[2], bias[2];
#pragma unroll
  for (int j = 0; j < 2; ++j) {
    int o = (nf0 + j) * 16 + ol;
    inv[j] = bnc[PASS * 128 + o];
    bias[j] = bnc[PASS * 128 + 64 + o];
  }

  bf16x8 wf[3][3][2][2];  // [kh][kw][ks][j] — compiler-managed residency (R6)
#pragma unroll
  for (int kh = 0; kh < 3; ++kh)
#pragma unroll
    for (int kw = 0; kw < 3; ++kw)
#pragma unroll
      for (int ks = 0; ks < 2; ++ks)
#pragma unroll
        for (int j = 0; j < 2; ++j)
          wf[kh][kw][ks][j] = __builtin_bit_cast(
              bf16x8, *reinterpret_cast<const u16x8*>(
                          weff + (((kh * 3 + kw) * 64 + (nf0 + j) * 16 + ol) * 64 +
                                  ks * 32 + kg * 8)));
  // no vmcnt(0) here: the S0 gate below subsumes it (wf loads are older)

  // tile decode (XCD-chunked: 784 blocks = 8 * 98, bijective)
  int sb = (blockIdx.x & 7) * 98 + (blockIdx.x >> 3);
  int tb[TILES], th0[TILES], tw0[TILES];
#pragma unroll
  for (int t = 0; t < TILES; ++t) {
    int tt = sb * TILES + t;
    tb[t] = tt / 98;
    int r = tt % 98;
    th0[t] = (r / 7) * 8;
    tw0[t] = (r % 7) * 16;
  }

  // stage one 10x18 window (1440 chunks; waves issue 6,6,6,5 insts)
  auto stage = [&](int t, int boff) {
#pragma unroll
    for (int k = 0; k < 6; ++k) {
      int i = wv + k * 4;
      if (i < 23) {
        int cb = i * 64 + lane;
        if (cb < 1440) {
          int row = cb / 144, rem = cb - row * 144;
          gl_lds16((const char*)(xin + (((long)tb[t] * PH + th0[t]) * PW + tw0[t]) * 64) +
                       (long)row * PROWB + rem * 16,
                   smem + boff + cb * 16);
        }
      }
    }
  };

  f32x4 acc[4][2];
  auto compute = [&](int boff) {
#pragma unroll
    for (int mf = 0; mf < 4; ++mf)
#pragma unroll
      for (int j = 0; j < 2; ++j) acc[mf][j] = f32x4{0.f, 0.f, 0.f, 0.f};
#pragma unroll
    for (int kw = 0; kw < 3; ++kw)
#pragma unroll
      for (int ks = 0; ks < 2; ++ks) {
        bf16x8 a[6];
#pragma unroll
        for (int u = 0; u < 6; ++u) {
          int rr = f0 + u, col = ol + kw;
          int slot = ((ks << 2) | kg) ^ ((2 * rr + col) & 7);
          a[u] = *reinterpret_cast<const bf16x8*>(smem + boff + (rr * 18 + col) * 128 +
                                                  slot * 16);
        }
#pragma unroll
        for (int kh = 0; kh < 3; ++kh)
#pragma unroll
          for (int mf = 0; mf < 4; ++mf)
#pragma unroll
            for (int j = 0; j < 2; ++j)
              acc[mf][j] = __builtin_amdgcn_mfma_f32_16x16x32_bf16(
                  a[mf + kh], wf[kh][kw][ks][j], acc[mf][j], 0, 0, 0);
      }
  };

  auto ysw = [&](int boff) {  // PASS0: bn1+relu -> bf16 transpose staging
    u16* ys = reinterpret_cast<u16*>(smem + boff);  // [128 px][72]
#pragma unroll
    for (int mf = 0; mf < 4; ++mf)
#pragma unroll
      for (int j = 0; j < 2; ++j) {
        int o = (nf0 + j) * 16 + ol;
#pragma unroll
        for (int rg = 0; rg < 4; ++rg) {
          int p = (f0 + mf) * 16 + kg * 4 + rg;
          ys[p * 72 + o] = f2b(fmaxf(acc[mf][j][rg] * inv[j] + bias[j], 0.f));
        }
      }
  };
  auto ysr = [&](int t, int boff) {  // coalesced swizzled NHWC store
    u16* ys = reinterpret_cast<u16*>(smem + boff);
#pragma unroll
    for (int it = 0; it < 4; ++it) {
      int cidx = it * 256 + tid;  // 1024 chunks
      int c8 = cidx & 7, p = cidx >> 3;
      int hp = th0[t] + (p >> 4) + 1, wp = tw0[t] + (p & 15) + 1;
      int gkey = (2 * hp + wp) & 7;
      *reinterpret_cast<u16x8*>(ypad + (((long)tb[t] * PH + hp) * PW + wp) * 64 +
                                ((c8 ^ gkey) * 8)) =
          *reinterpret_cast<const u16x8*>(ys + p * 72 + c8 * 8);
    }
  };

  // ---- prologue ----
  stage(0, 0);
  stage(1, BUFB);
  if (wv < 3) WAITVM(6); else WAITVM(5);  // S0 done (younger loads = S1)
  SCHEDB;
  __builtin_amdgcn_s_barrier();
  SCHEDB;

#pragma unroll
  for (int t = 0; t < TILES; ++t) {
    const int boff = (t & 1) * BUFB;
    compute(boff);
    SCHEDB;
    __builtin_amdgcn_s_barrier();  // all waves done reading buf_t
    SCHEDB;

    if constexpr (PASS == 0) {
      ysw(boff);
      asm volatile("s_waitcnt lgkmcnt(0)" ::: "memory");
      SCHEDB;
      __builtin_amdgcn_s_barrier();
      SCHEDB;
      ysr(t, boff);
      if (t < TILES - 1) {
        __builtin_amdgcn_s_barrier();  // ysr LDS reads done -> buf_t reusable
        SCHEDB;
        if (t + 2 < TILES) {
          stage(t + 2, boff);
          if (wv < 3) WAITVM(6); else WAITVM(5);  // S_{t+1} done (younger=stage)
        } else {
          WAITVM(0);  // S_{t+1} done (no younger loads exist)
        }
        SCHEDB;
        __builtin_amdgcn_s_barrier();
        SCHEDB;
      }
    } else {
      // epilogue loads FIRST, then re-stage, then consume: compiler waits for
      // xr count the 6 younger stage loads -> vmcnt(6), stage stays in flight.
      f32x4 xr[2][2][2];
#pragma unroll
      for (int half = 0; half < 2; ++half)
#pragma unroll
        for (int m = 0; m < 2; ++m)
#pragma unroll
          for (int j = 0; j < 2; ++j) {
            int h = th0[t] + f0 + half * 2 + m;
            xr[half][m][j] = *reinterpret_cast<const f32x4*>(
                x + (((tb[t] * 64 + (nf0 + j) * 16 + ol) * NH + h) * NW + tw0[t] + kg * 4));
          }
      if (t + 2 < TILES) stage(t + 2, boff);
#pragma unroll
      for (int half = 0; half < 2; ++half)
#pragma unroll
        for (int m = 0; m < 2; ++m) {
          int mf = half * 2 + m;
          int h = th0[t] + f0 + mf;
#pragma unroll
          for (int j = 0; j < 2; ++j) {
            f32x4 vv;
#pragma unroll
            for (int rg = 0; rg < 4; ++rg)
              vv[rg] = fmaxf(acc[mf][j][rg] * inv[j] + bias[j] + xr[half][m][j][rg], 0.f);
            *reinterpret_cast<f32x4*>(
                out + (((tb[t] * 64 + (nf0 + j) * 16 + ol) * NH + h) * NW + tw0[t] + kg * 4)) =
                vv;
          }
        }
      if (t < TILES - 1) {
        // S_{t+1} gate: younger loads = 8 xr + stage(t+2) (6|5) or 0
        if (t + 2 < TILES) { if (wv < 3) WAITVM(14); else WAITVM(13); }
        else WAITVM(8);
        SCHEDB;
        __builtin_amdgcn_s_barrier();
        SCHEDB;
      }
    }
  }
}

// ---------------------------------------------------------------------------
extern "C" void kernel_launch(void* const* d_in, const int* in_sizes, int n_in,
                              void* d_out, int out_size, void* d_ws, size_t ws_size,
                              hipStream_t stream) {
  const float* x = (const float*)d_in[0];
  const float* w1 = (const float*)d_in[1];
  const float* w2 = (const float*)d_in[2];
  const float* alpha = (const float*)d_in[3];
  const float* g1 = (const float*)d_in[4];
  const float* b1 = (const float*)d_in[5];
  const float* m1 = (const float*)d_in[6];
  const float* v1 = (const float*)d_in[7];
  const float* g2 = (const float*)d_in[8];
  const float* b2 = (const float*)d_in[9];
  const float* m2 = (const float*)d_in[10];
  const float* v2 = (const float*)d_in[11];
  float* out = (float*)d_out;

  char* ws = (char*)d_ws;
  u16* weff1 = (u16*)ws;                 // 73728 B
  u16* weff2 = (u16*)(ws + 73728);       // 73728 B
  float* bnc = (float*)(ws + 147456);    // 1024 B
  u16* y1pad = (u16*)(ws + 148480);      // 32*114*114*64*2 = 53231616 B
  u16* xpad = (u16*)d_out;               // 53 MB <= 103 MB; dead before P1 writes

  border_zero<<<904, 256, 0, stream>>>(xpad, y1pad);
  transform_kernel<<<32 * NH, 256, 0, stream>>>(x, xpad);
  prep_kernel<<<144, 256, 0, stream>>>(w1, w2, alpha, g1, b1, m1, v1,
                                       g2, b2, m2, v2, weff1, weff2, bnc);
  conv_bn_kernel<0, 4><<<784, 256, 0, stream>>>(xpad, x, weff1, bnc, y1pad, nullptr);
  conv_bn_kernel<1, 4><<<784, 256, 0, stream>>>(y1pad, x, weff2, bnc, nullptr, out);
}